// Round 12
// baseline (181.663 us; speedup 1.0000x reference)
//
#include <hip/hip_runtime.h>
#include <hip/hip_bf16.h>
#include <stdint.h>

#define N_ROWS 16384
#define K_DIM  1024
#define N_OUT  4096

typedef __attribute__((ext_vector_type(8))) short short8;
typedef __attribute__((ext_vector_type(4))) float f32x4;
typedef __attribute__((ext_vector_type(4))) __bf16 bf16x4;

// ---------------- mask compaction: idx (active rows), zidx (masked), count ----
__global__ __launch_bounds__(1024) void scan_kernel(const int* __restrict__ amask,
                                                    int* __restrict__ idx,
                                                    int* __restrict__ zidx,
                                                    int* __restrict__ count) {
    __shared__ int sc[1024];
    const int t = threadIdx.x;
    const int base = t * 16;
    int mk[16];
#pragma unroll
    for (int g = 0; g < 4; ++g) {
        int4 m4 = reinterpret_cast<const int4*>(amask + base)[g];
        mk[g*4+0] = m4.x; mk[g*4+1] = m4.y; mk[g*4+2] = m4.z; mk[g*4+3] = m4.w;
    }
    int c = 0;
#pragma unroll
    for (int i = 0; i < 16; ++i) c += (mk[i] != 0) ? 1 : 0;
    int v = c;
    sc[t] = v;
    __syncthreads();
    for (int off = 1; off < 1024; off <<= 1) {       // Hillis-Steele scan
        int u = (t >= off) ? sc[t - off] : 0;
        __syncthreads();
        v += u; sc[t] = v;
        __syncthreads();
    }
    int b  = v - c;
    int zb = base - b;
#pragma unroll
    for (int i = 0; i < 16; ++i) {
        int r = base + i;
        if (mk[i] != 0) idx[b++] = r; else zidx[zb++] = r;
    }
    if (t == 1023) count[0] = v;
}

// ---- cvtW + gather-x (merged, after scan): blocks 0..255 convert W dense;
//      blocks 256..2303 gather-convert active x rows into compacted xb. -------
__global__ __launch_bounds__(256) void cvtw_gather_kernel(
    const float* __restrict__ W, const float* __restrict__ x,
    const int* __restrict__ idx, const int* __restrict__ count,
    __bf16* __restrict__ wb, __bf16* __restrict__ xb) {
    const int t = threadIdx.x;
    if (blockIdx.x < 256) {
        // W: 1M float4 over 256 blocks x 256 threads x 16 iters
        const int base = blockIdx.x * 4096 + t;
#pragma unroll
        for (int it = 0; it < 16; ++it) {
            const int i = base + it * 256;
            float4 v = reinterpret_cast<const float4*>(W)[i];
            bf16x4 o;
            o[0] = (__bf16)v.x; o[1] = (__bf16)v.y; o[2] = (__bf16)v.z; o[3] = (__bf16)v.w;
            reinterpret_cast<bf16x4*>(wb)[i] = o;
        }
        return;
    }
    const int cnt = count[0];
    for (int j = blockIdx.x - 256; j < cnt; j += 2048) {
        const int row = idx[j];
        float4 v = reinterpret_cast<const float4*>(x + (size_t)row * K_DIM)[t];
        bf16x4 o;
        o[0] = (__bf16)v.x; o[1] = (__bf16)v.y; o[2] = (__bf16)v.z; o[3] = (__bf16)v.w;
        reinterpret_cast<bf16x4*>(xb + (size_t)j * K_DIM)[t] = o;
    }
}

// ---------------- compacted 128x128 m97-structure GEMM, BK=64, zfill fold -----
// Heavy mapping EXACTLY R10 (tn fast, tm slow). Changes vs R10:
//  (1) BK=64: LDS A[128][64]+B[128][64] = 32 KB, halves barrier count per K
//      (2-phase critical path = stage+drain+barrier; ds cost per K unchanged).
//  (2) trivial blocks (tm >= aT) zero-fill masked rows instead of exiting —
//      their 128 MB of writes hide under the compute-bound heavy blocks
//      (GEMM dispatch ran at only ~1.6 TB/s HBM; plenty of headroom).

#define GLL(SRC, DSTOFF)                                                       \
    __builtin_amdgcn_global_load_lds(                                          \
        (const __attribute__((address_space(1))) void*)(SRC),                  \
        (__attribute__((address_space(3))) void*)(ldsc + (DSTOFF)), 16, 0, 0)

__global__ __launch_bounds__(256) void gemm_kernel(
    const __bf16* __restrict__ A,      // compacted active rows
    const __bf16* __restrict__ B,
    const float*  __restrict__ bias,
    const int*    __restrict__ idx,
    const int*    __restrict__ zidx,
    const int*    __restrict__ count,
    float*        __restrict__ out)
{
    __shared__ short lds_all[16384];   // 32 KB: A [128][64] @0, B [128][64] @16384B

    const int cnt = count[0];
    const int aT  = (cnt + 127) >> 7;  // active row-tiles of 128
    const int tn  = blockIdx.x & 31;   // fast axis (R10 mapping)
    const int tm  = blockIdx.x >> 5;   // 0..127
    const int t   = threadIdx.x;

    if (tm >= aT) {
        // ---- zero-fill role: rank over trivial blocks, full 16KB rows ----
        const int ntriv = 4096 - aT * 32;          // >= 1 here
        const int tr    = blockIdx.x - aT * 32;    // 0..ntriv-1
        const int nz    = N_ROWS - cnt;
        const float4 zf = make_float4(0.f, 0.f, 0.f, 0.f);
        for (int i = tr; i < nz; i += ntriv) {
            const int row = zidx[i];
            float4* p = reinterpret_cast<float4*>(out + (size_t)row * N_OUT);
#pragma unroll
            for (int u = 0; u < 4; ++u)            // 256 thr x 4 float4 = 16 KB
                p[u * 256 + t] = zf;
        }
        return;
    }

    const int l  = t & 63;
    const int w  = t >> 6;             // wave 0..3
    const int wm = w >> 1;             // 0..1
    const int wn = w & 1;              // 0..1

    const int m0 = tm * 128;           // base in COMPACTED row space
    const int n0 = tn * 128;

    // Coalesced staging for BK=64: thread t stages row (t>>3), chunk (t&7)*16B
    // of a 128B row; pass p adds 32 rows. Dest p*4096 + t*16 is row-linear.
    const int srow = t >> 3;
    const int sk   = (t & 7) * 8;
    const __bf16* pA = A + (size_t)(m0 + srow) * K_DIM + sk;
    const __bf16* pB = B + (size_t)(n0 + srow) * K_DIM + sk;
    char* ldsc = (char*)lds_all;

    const int lr  = l & 15;            // fragment row lane index
    const int lqb = (l >> 4) * 16;     // k-group byte offset within 64B half-row

    f32x4 acc[4][4] = {};

    for (int k0 = 0; k0 < K_DIM; k0 += 64) {
#pragma unroll
        for (int p = 0; p < 4; ++p) {
            GLL(pA + k0 + (size_t)(p * 32) * K_DIM, p * 4096 + t * 16);
            GLL(pB + k0 + (size_t)(p * 32) * K_DIM, 16384 + p * 4096 + t * 16);
        }
        __syncthreads();                // drains vmcnt before barrier

#pragma unroll
        for (int s = 0; s < 2; ++s) {   // two 32-wide k-steps per tile
            short8 af[4], bf[4];
#pragma unroll
            for (int mi = 0; mi < 4; ++mi)
                af[mi] = *(const short8*)((char*)lds_all +
                         (wm*64 + mi*16 + lr) * 128 + s * 64 + lqb);
#pragma unroll
            for (int ni = 0; ni < 4; ++ni)
                bf[ni] = *(const short8*)((char*)lds_all + 16384 +
                         (wn*64 + ni*16 + lr) * 128 + s * 64 + lqb);

#pragma unroll
            for (int mi = 0; mi < 4; ++mi)
#pragma unroll
                for (int ni = 0; ni < 4; ++ni)
                    acc[mi][ni] = __builtin_amdgcn_mfma_f32_16x16x32_bf16(
                        af[mi], bf[ni], acc[mi][ni], 0, 0, 0);
        }
        __syncthreads();
    }

    // Epilogue: bias add, scatter to original rows, guard padded slots.
    const int lq = l >> 4;
    float bv[4];
#pragma unroll
    for (int ni = 0; ni < 4; ++ni) bv[ni] = bias[n0 + wn*64 + ni*16 + lr];

#pragma unroll
    for (int mi = 0; mi < 4; ++mi) {
        const int slot0 = m0 + wm*64 + mi*16 + lq*4;
        int rowid[4]; bool val[4];
#pragma unroll
        for (int r = 0; r < 4; ++r) {
            const int s = slot0 + r;
            val[r] = (s < cnt);
            rowid[r] = val[r] ? idx[s] : 0;
        }
#pragma unroll
        for (int ni = 0; ni < 4; ++ni) {
            const int cc = n0 + wn*64 + ni*16 + lr;
#pragma unroll
            for (int r = 0; r < 4; ++r)
                if (val[r]) out[(size_t)rowid[r] * N_OUT + cc] = acc[mi][ni][r] + bv[ni];
        }
    }
}

// ---------------- naive fp32 fallback (only if ws too small) ------------------
__global__ void naive_kernel(const float* __restrict__ x, const float* __restrict__ W,
                             const float* __restrict__ bias, const int* __restrict__ amask,
                             float* __restrict__ out) {
    int c = blockIdx.x * blockDim.x + threadIdx.x;
    int r = blockIdx.y;
    if (c >= N_OUT) return;
    if (amask[r] == 0) { out[(size_t)r * N_OUT + c] = 0.0f; return; }
    const float* xr = x + (size_t)r * K_DIM;
    const float* wr = W + (size_t)c * K_DIM;
    float s = 0.0f;
    for (int k = 0; k < K_DIM; ++k) s += xr[k] * wr[k];
    out[(size_t)r * N_OUT + c] = s + bias[c];
}

extern "C" void kernel_launch(void* const* d_in, const int* in_sizes, int n_in,
                              void* d_out, int out_size, void* d_ws, size_t ws_size,
                              hipStream_t stream) {
    const float* x     = (const float*)d_in[0];
    const int*   amask = (const int*)d_in[1];
    const float* W     = (const float*)d_in[2];
    const float* bias  = (const float*)d_in[3];
    float*       out   = (float*)d_out;

    const size_t xb_bytes = (size_t)N_ROWS * K_DIM * 2;   // 32 MB
    const size_t wb_bytes = (size_t)N_OUT  * K_DIM * 2;   //  8 MB
    const size_t idx_bytes = (size_t)N_ROWS * 4;          // 64 KB
    const size_t need = xb_bytes + wb_bytes + 2 * idx_bytes + 256;

    if (ws_size < need) {
        dim3 g((N_OUT + 255) / 256, N_ROWS);
        naive_kernel<<<g, 256, 0, stream>>>(x, W, bias, amask, out);
        return;
    }

    __bf16* xb   = (__bf16*)d_ws;
    __bf16* wb   = (__bf16*)((char*)d_ws + xb_bytes);
    int*    idx  = (int*)((char*)d_ws + xb_bytes + wb_bytes);
    int*    zidx = idx + N_ROWS;
    int*    cnt  = zidx + N_ROWS;

    scan_kernel<<<1, 1024, 0, stream>>>(amask, idx, zidx, cnt);
    cvtw_gather_kernel<<<2304, 256, 0, stream>>>(W, x, idx, cnt, wb, xb);
    gemm_kernel<<<4096, 256, 0, stream>>>(xb, wb, bias, idx, zidx, cnt, out);
}

// Round 13
// 148.510 us; speedup vs baseline: 1.2232x; 1.2232x over previous
//
#include <hip/hip_runtime.h>
#include <hip/hip_bf16.h>
#include <stdint.h>

#define N_ROWS 16384
#define K_DIM  1024
#define N_OUT  4096

typedef __attribute__((ext_vector_type(8))) short short8;
typedef __attribute__((ext_vector_type(4))) float f32x4;
typedef __attribute__((ext_vector_type(4))) __bf16 bf16x4;

// ---------------- prep: block 0 = mask scan, blocks 1..1024 = cvt W -----------
__global__ __launch_bounds__(1024) void prep_kernel(
    const int*   __restrict__ amask,
    const float* __restrict__ W,
    int* __restrict__ idx, int* __restrict__ zidx, int* __restrict__ count,
    __bf16* __restrict__ wb)
{
    const int t = threadIdx.x;
    if (blockIdx.x != 0) {
        const int i = (blockIdx.x - 1) * 1024 + t;   // < 1,048,576 float4
        float4 v = reinterpret_cast<const float4*>(W)[i];
        bf16x4 o;
        o[0] = (__bf16)v.x; o[1] = (__bf16)v.y; o[2] = (__bf16)v.z; o[3] = (__bf16)v.w;
        reinterpret_cast<bf16x4*>(wb)[i] = o;
        return;
    }
    __shared__ int sc[1024];
    const int base = t * 16;
    int mk[16];
#pragma unroll
    for (int g = 0; g < 4; ++g) {
        int4 m4 = reinterpret_cast<const int4*>(amask + base)[g];
        mk[g*4+0] = m4.x; mk[g*4+1] = m4.y; mk[g*4+2] = m4.z; mk[g*4+3] = m4.w;
    }
    int c = 0;
#pragma unroll
    for (int i = 0; i < 16; ++i) c += (mk[i] != 0) ? 1 : 0;
    int v = c;
    sc[t] = v;
    __syncthreads();
    for (int off = 1; off < 1024; off <<= 1) {       // Hillis-Steele scan
        int u = (t >= off) ? sc[t - off] : 0;
        __syncthreads();
        v += u; sc[t] = v;
        __syncthreads();
    }
    int b  = v - c;
    int zb = base - b;
#pragma unroll
    for (int i = 0; i < 16; ++i) {
        int r = base + i;
        if (mk[i] != 0) idx[b++] = r; else zidx[zb++] = r;
    }
    if (t == 1023) count[0] = v;
}

// ---------------- gather: xb[j] = bf16(x[idx[j]]), j < cnt --------------------
__global__ __launch_bounds__(256) void gather_kernel(
    const float* __restrict__ x, const int* __restrict__ idx,
    const int* __restrict__ count, __bf16* __restrict__ xb) {
    const int t = threadIdx.x;                   // 256 threads = 256 float4/row
    const int cnt = count[0];
    for (int j = blockIdx.x; j < cnt; j += 2048) {
        const int row = idx[j];
        float4 v = reinterpret_cast<const float4*>(x + (size_t)row * K_DIM)[t];
        bf16x4 o;
        o[0] = (__bf16)v.x; o[1] = (__bf16)v.y; o[2] = (__bf16)v.z; o[3] = (__bf16)v.w;
        reinterpret_cast<bf16x4*>(xb + (size_t)j * K_DIM)[t] = o;
    }
}

// ---------------- compacted 128x128 m97-structure bf16 MFMA GEMM --------------
// EXACT R10 heavy path (best measured: BK=32, [128][32] LDS, plain mapping
// tn fast / tm slow). Single change vs R10: trivial blocks (tm >= aT), which
// are dispatched AFTER all heavy blocks, zero-fill masked rows (full 16KB
// rows, float4) instead of exiting — their 128 MB of writes ride the heavy
// phase's BW headroom (GEMM runs at only ~0.6-2.2 TB/s) and the tail,
// removing ~20 us of zfill from the serial gather stage.

#define GLL(SRC, DSTOFF)                                                       \
    __builtin_amdgcn_global_load_lds(                                          \
        (const __attribute__((address_space(1))) void*)(SRC),                  \
        (__attribute__((address_space(3))) void*)(ldsc + (DSTOFF)), 16, 0, 0)

__global__ __launch_bounds__(256) void gemm_kernel(
    const __bf16* __restrict__ A,      // compacted active rows
    const __bf16* __restrict__ B,
    const float*  __restrict__ bias,
    const int*    __restrict__ idx,
    const int*    __restrict__ zidx,
    const int*    __restrict__ count,
    float*        __restrict__ out)
{
    __shared__ short lds_all[8192];    // 16 KB: A [128][32] @0, B [128][32] @8192B

    const int cnt = count[0];
    const int aT  = (cnt + 127) >> 7;  // active row-tiles of 128
    const int tn  = blockIdx.x & 31;   // fast axis (R10 mapping)
    const int tm  = blockIdx.x >> 5;   // 0..127
    const int t   = threadIdx.x;

    if (tm >= aT) {
        // ---- zero-fill role (runs after heavy blocks in dispatch order) ----
        const int ntriv = 4096 - aT * 32;          // >= 1 here
        const int tr    = blockIdx.x - aT * 32;    // 0..ntriv-1
        const int nz    = N_ROWS - cnt;
        const float4 zf = make_float4(0.f, 0.f, 0.f, 0.f);
        for (int i = tr; i < nz; i += ntriv) {
            const int row = zidx[i];
            float4* p = reinterpret_cast<float4*>(out + (size_t)row * N_OUT);
#pragma unroll
            for (int u = 0; u < 4; ++u)            // 256 thr x 4 float4 = 16 KB
                p[u * 256 + t] = zf;
        }
        return;
    }

    const int l  = t & 63;
    const int w  = t >> 6;             // wave 0..3
    const int wm = w >> 1;             // 0..1
    const int wn = w & 1;              // 0..1

    const int m0 = tm * 128;           // base in COMPACTED row space
    const int n0 = tn * 128;

    // R1-style coalesced staging: thread t stages row (t>>2), k8 = (t&3)*8.
    const int srow = t >> 2;
    const int sk8  = (t & 3) * 8;
    const __bf16* pA0 = A + (size_t)(m0 + srow) * K_DIM + sk8;
    const __bf16* pA1 = pA0 + (size_t)64 * K_DIM;
    const __bf16* pB0 = B + (size_t)(n0 + srow) * K_DIM + sk8;
    const __bf16* pB1 = pB0 + (size_t)64 * K_DIM;
    char* ldsc = (char*)lds_all;

    const int lr = l & 15;
    const int lk = (l >> 4) * 8;

    f32x4 acc[4][4] = {};

    for (int k0 = 0; k0 < K_DIM; k0 += 32) {
        GLL(pA0 + k0, t * 16);
        GLL(pA1 + k0, 4096 + t * 16);
        GLL(pB0 + k0, 8192 + t * 16);
        GLL(pB1 + k0, 12288 + t * 16);
        __syncthreads();

        short8 af[4], bf[4];
#pragma unroll
        for (int mi = 0; mi < 4; ++mi)
            af[mi] = *(const short8*)(lds_all + (wm*64 + mi*16 + lr)*32 + lk);
#pragma unroll
        for (int ni = 0; ni < 4; ++ni)
            bf[ni] = *(const short8*)(lds_all + 4096 + (wn*64 + ni*16 + lr)*32 + lk);

#pragma unroll
        for (int mi = 0; mi < 4; ++mi)
#pragma unroll
            for (int ni = 0; ni < 4; ++ni)
                acc[mi][ni] = __builtin_amdgcn_mfma_f32_16x16x32_bf16(
                    af[mi], bf[ni], acc[mi][ni], 0, 0, 0);
        __syncthreads();
    }

    // Epilogue: bias add, scatter to original rows, guard padded slots.
    const int lq = l >> 4;
    float bv[4];
#pragma unroll
    for (int ni = 0; ni < 4; ++ni) bv[ni] = bias[n0 + wn*64 + ni*16 + lr];

#pragma unroll
    for (int mi = 0; mi < 4; ++mi) {
        const int slot0 = m0 + wm*64 + mi*16 + lq*4;
        int rowid[4]; bool val[4];
#pragma unroll
        for (int r = 0; r < 4; ++r) {
            const int s = slot0 + r;
            val[r] = (s < cnt);
            rowid[r] = val[r] ? idx[s] : 0;
        }
#pragma unroll
        for (int ni = 0; ni < 4; ++ni) {
            const int cc = n0 + wn*64 + ni*16 + lr;
#pragma unroll
            for (int r = 0; r < 4; ++r)
                if (val[r]) out[(size_t)rowid[r] * N_OUT + cc] = acc[mi][ni][r] + bv[ni];
        }
    }
}

// ---------------- naive fp32 fallback (only if ws too small) ------------------
__global__ void naive_kernel(const float* __restrict__ x, const float* __restrict__ W,
                             const float* __restrict__ bias, const int* __restrict__ amask,
                             float* __restrict__ out) {
    int c = blockIdx.x * blockDim.x + threadIdx.x;
    int r = blockIdx.y;
    if (c >= N_OUT) return;
    if (amask[r] == 0) { out[(size_t)r * N_OUT + c] = 0.0f; return; }
    const float* xr = x + (size_t)r * K_DIM;
    const float* wr = W + (size_t)c * K_DIM;
    float s = 0.0f;
    for (int k = 0; k < K_DIM; ++k) s += xr[k] * wr[k];
    out[(size_t)r * N_OUT + c] = s + bias[c];
}

extern "C" void kernel_launch(void* const* d_in, const int* in_sizes, int n_in,
                              void* d_out, int out_size, void* d_ws, size_t ws_size,
                              hipStream_t stream) {
    const float* x     = (const float*)d_in[0];
    const int*   amask = (const int*)d_in[1];
    const float* W     = (const float*)d_in[2];
    const float* bias  = (const float*)d_in[3];
    float*       out   = (float*)d_out;

    const size_t xb_bytes = (size_t)N_ROWS * K_DIM * 2;   // 32 MB
    const size_t wb_bytes = (size_t)N_OUT  * K_DIM * 2;   //  8 MB
    const size_t idx_bytes = (size_t)N_ROWS * 4;          // 64 KB
    const size_t need = xb_bytes + wb_bytes + 2 * idx_bytes + 256;

    if (ws_size < need) {
        dim3 g((N_OUT + 255) / 256, N_ROWS);
        naive_kernel<<<g, 256, 0, stream>>>(x, W, bias, amask, out);
        return;
    }

    __bf16* xb   = (__bf16*)d_ws;
    __bf16* wb   = (__bf16*)((char*)d_ws + xb_bytes);
    int*    idx  = (int*)((char*)d_ws + xb_bytes + wb_bytes);
    int*    zidx = idx + N_ROWS;
    int*    cnt  = zidx + N_ROWS;

    prep_kernel<<<1025, 1024, 0, stream>>>(amask, W, idx, zidx, cnt, wb);
    gather_kernel<<<2048, 256, 0, stream>>>(x, idx, cnt, xb);
    gemm_kernel<<<4096, 256, 0, stream>>>(xb, wb, bias, idx, zidx, cnt, out);
}